// Round 1
// baseline (17150.592 us; speedup 1.0000x reference)
//
#include <hip/hip_runtime.h>
#include <math.h>

#define HID   128
#define NPT   50000
#define BATCH 8

__device__ __forceinline__ float sigm(float x) {
    // 1 / (1 + e^-x) via fast exp + fast divide
    return __fdividef(1.0f, 1.0f + __expf(-x));
}

__device__ __forceinline__ float tanh_fast(float x) {
    // tanh(x) = (e^{2x} - 1) / (e^{2x} + 1); clamp to avoid inf/inf (tanh saturated anyway)
    float xc = fminf(fmaxf(x, -15.0f), 15.0f);
    float e  = __expf(2.0f * xc);
    return __fdividef(e - 1.0f, e + 1.0f);
}

__global__ void node_rk4_kernel(
    const float* __restrict__ x0,
    const float* __restrict__ h1_w, const float* __restrict__ h1_b,
    const float* __restrict__ g1_w, const float* __restrict__ g1_b,
    const float* __restrict__ h2_w, const float* __restrict__ h2_b,
    const float* __restrict__ g2_w, const float* __restrict__ g2_b,
    const float* __restrict__ out_w, const float* __restrict__ out_b,
    float* __restrict__ y)
{
    const int p = blockIdx.x * blockDim.x + threadIdx.x;
    const int total = BATCH * NPT;
    if (p >= total) return;

    const int b = p / NPT;              // constant divisor -> magic multiply
    const int n = p - b * NPT;
    const size_t base = (size_t)b * 3 * NPT + n;

    const float xc0 = x0[base];
    const float xc1 = x0[base + NPT];
    const float xc2 = x0[base + 2 * NPT];

    const float third = 1.0f / 3.0f;

    float k1x = 0.f, k1y = 0.f, k1z = 0.f;
    float k2x = 0.f, k2y = 0.f, k2z = 0.f;
    float k3x = 0.f, k3y = 0.f, k3z = 0.f;
    float ax = 0.f, ay = 0.f, az = 0.f;

    // 3/8-rule RK4: 4 field evaluations. Loop (not unrolled) to keep the
    // field body resident in L1I once (~20 KB).
    #pragma unroll 1
    for (int s = 0; s < 4; ++s) {
        float zi0, zi1, zi2, t;
        if (s == 0) {
            zi0 = xc0; zi1 = xc1; zi2 = xc2; t = 0.0f;
        } else if (s == 1) {
            zi0 = fmaf(k1x, third, xc0);
            zi1 = fmaf(k1y, third, xc1);
            zi2 = fmaf(k1z, third, xc2);
            t = third;
        } else if (s == 2) {
            zi0 = xc0 + (k2x - k1x * third);
            zi1 = xc1 + (k2y - k1y * third);
            zi2 = xc2 + (k2z - k1z * third);
            t = 2.0f * third;
        } else {
            zi0 = xc0 + (k1x - k2x + k3x);
            zi1 = xc1 + (k1y - k2y + k3y);
            zi2 = xc2 + (k1z - k2z + k3z);
            t = 1.0f;
        }

        // ---- layer 1: 4 -> 128, gated (fully unrolled: z1[o] must be VGPRs) ----
        float z1[HID];
        #pragma unroll
        for (int o = 0; o < HID; ++o) {
            const float* hw = h1_w + o * 4;   // wave-uniform -> s_load
            const float* gw = g1_w + o * 4;
            float h = fmaf(hw[0], zi0, fmaf(hw[1], zi1, fmaf(hw[2], zi2, fmaf(hw[3], t, h1_b[o]))));
            float g = fmaf(gw[0], zi0, fmaf(gw[1], zi1, fmaf(gw[2], zi2, fmaf(gw[3], t, g1_b[o]))));
            z1[o] = fmaxf(h * sigm(g), 0.0f);
        }

        // ---- layer 2: 128 -> 128 gated, fused with out layer (128 -> 3) ----
        float v0 = out_b[0], v1 = out_b[1], v2 = out_b[2];
        #pragma unroll 1
        for (int o = 0; o < HID; ++o) {
            float h = h2_b[o];
            float g = g2_b[o];
            const float* hw = h2_w + o * HID;  // wave-uniform rows -> s_load_dwordx16
            const float* gw = g2_w + o * HID;
            #pragma unroll
            for (int i = 0; i < HID; ++i) {
                h = fmaf(hw[i], z1[i], h);
                g = fmaf(gw[i], z1[i], g);
            }
            float a = fmaxf(h * sigm(g), 0.0f);
            v0 = fmaf(out_w[o],           a, v0);
            v1 = fmaf(out_w[HID + o],     a, v1);
            v2 = fmaf(out_w[2 * HID + o], a, v2);
        }

        const float kx = tanh_fast(v0) * 0.5f;
        const float ky = tanh_fast(v1) * 0.5f;
        const float kz = tanh_fast(v2) * 0.5f;

        if (s == 0) {
            k1x = kx; k1y = ky; k1z = kz;
            ax = kx; ay = ky; az = kz;
        } else if (s == 1) {
            k2x = kx; k2y = ky; k2z = kz;
            ax = fmaf(3.0f, kx, ax); ay = fmaf(3.0f, ky, ay); az = fmaf(3.0f, kz, az);
        } else if (s == 2) {
            k3x = kx; k3y = ky; k3z = kz;
            ax = fmaf(3.0f, kx, ax); ay = fmaf(3.0f, ky, ay); az = fmaf(3.0f, kz, az);
        } else {
            ax += kx; ay += ky; az += kz;
        }
    }

    y[base]           = fmaf(0.125f, ax, xc0);
    y[base + NPT]     = fmaf(0.125f, ay, xc1);
    y[base + 2 * NPT] = fmaf(0.125f, az, xc2);
}

extern "C" void kernel_launch(void* const* d_in, const int* in_sizes, int n_in,
                              void* d_out, int out_size, void* d_ws, size_t ws_size,
                              hipStream_t stream) {
    (void)in_sizes; (void)n_in; (void)d_ws; (void)ws_size; (void)out_size;
    const float* x0    = (const float*)d_in[0];
    const float* h1_w  = (const float*)d_in[1];
    const float* h1_b  = (const float*)d_in[2];
    const float* g1_w  = (const float*)d_in[3];
    const float* g1_b  = (const float*)d_in[4];
    const float* h2_w  = (const float*)d_in[5];
    const float* h2_b  = (const float*)d_in[6];
    const float* g2_w  = (const float*)d_in[7];
    const float* g2_b  = (const float*)d_in[8];
    const float* out_w = (const float*)d_in[9];
    const float* out_b = (const float*)d_in[10];
    float* y = (float*)d_out;

    const int total = BATCH * NPT;
    const int block = 256;
    const int grid  = (total + block - 1) / block;
    node_rk4_kernel<<<grid, block, 0, stream>>>(
        x0, h1_w, h1_b, g1_w, g1_b, h2_w, h2_b, g2_w, g2_b, out_w, out_b, y);
}

// Round 2
// 2546.308 us; speedup vs baseline: 6.7355x; 6.7355x over previous
//
#include <hip/hip_runtime.h>
#include <math.h>
#include <utility>

#define HID   128
#define NPT   50000
#define BATCH 8

// Compile-time for: indices are constexpr at IR-gen time, so the z1 alloca is
// only ever addressed with constant GEPs -> SROA scalarizes it into SSA values
// (VGPRs) regardless of pass ordering. (Round-1 failure: pragma-unroll happens
// AFTER SROA, so dynamic indices left z1 in scratch -> 57 GB HBM traffic.)
template<int I, int N, class F>
__device__ __forceinline__ void sfor(F&& f) {
    if constexpr (I < N) {
        f(std::integral_constant<int, I>{});
        sfor<I + 1, N>(static_cast<F&&>(f));
    }
}

__device__ __forceinline__ float sigm(float x) {
    return __fdividef(1.0f, 1.0f + __expf(-x));
}

__device__ __forceinline__ float tanh_fast(float x) {
    float xc = fminf(fmaxf(x, -15.0f), 15.0f);
    float e  = __expf(2.0f * xc);
    return __fdividef(e - 1.0f, e + 1.0f);
}

__global__ __launch_bounds__(256, 2) void node_rk4_kernel(
    const float* __restrict__ x0,
    const float* __restrict__ h1_w, const float* __restrict__ h1_b,
    const float* __restrict__ g1_w, const float* __restrict__ g1_b,
    const float* __restrict__ h2_w, const float* __restrict__ h2_b,
    const float* __restrict__ g2_w, const float* __restrict__ g2_b,
    const float* __restrict__ out_w, const float* __restrict__ out_b,
    float* __restrict__ y)
{
    const int p = blockIdx.x * blockDim.x + threadIdx.x;
    const int total = BATCH * NPT;
    if (p >= total) return;

    const int b = p / NPT;
    const int n = p - b * NPT;
    const size_t base = (size_t)b * 3 * NPT + n;

    const float xc0 = x0[base];
    const float xc1 = x0[base + NPT];
    const float xc2 = x0[base + 2 * NPT];

    const float third = 1.0f / 3.0f;

    float k1x = 0.f, k1y = 0.f, k1z = 0.f;
    float k2x = 0.f, k2y = 0.f, k2z = 0.f;
    float k3x = 0.f, k3y = 0.f, k3z = 0.f;
    float ax = 0.f, ay = 0.f, az = 0.f;

    #pragma unroll 1
    for (int s = 0; s < 4; ++s) {
        float zi0, zi1, zi2, t;
        if (s == 0) {
            zi0 = xc0; zi1 = xc1; zi2 = xc2; t = 0.0f;
        } else if (s == 1) {
            zi0 = fmaf(k1x, third, xc0);
            zi1 = fmaf(k1y, third, xc1);
            zi2 = fmaf(k1z, third, xc2);
            t = third;
        } else if (s == 2) {
            zi0 = xc0 + (k2x - k1x * third);
            zi1 = xc1 + (k2y - k1y * third);
            zi2 = xc2 + (k2z - k1z * third);
            t = 2.0f * third;
        } else {
            zi0 = xc0 + (k1x - k2x + k3x);
            zi1 = xc1 + (k1y - k2y + k3y);
            zi2 = xc2 + (k1z - k2z + k3z);
            t = 1.0f;
        }

        // ---- layer 1: 4 -> 128, gated. Constant indices everywhere. ----
        float z1[HID];
        sfor<0, HID>([&](auto oc) {
            constexpr int o = decltype(oc)::value;
            float h = fmaf(h1_w[o*4+0], zi0, fmaf(h1_w[o*4+1], zi1,
                      fmaf(h1_w[o*4+2], zi2, fmaf(h1_w[o*4+3], t, h1_b[o]))));
            float g = fmaf(g1_w[o*4+0], zi0, fmaf(g1_w[o*4+1], zi1,
                      fmaf(g1_w[o*4+2], zi2, fmaf(g1_w[o*4+3], t, g1_b[o]))));
            z1[o] = fmaxf(h * sigm(g), 0.0f);
        });

        // ---- layer 2 (128->128 gated) fused with out layer (128->3) ----
        // o is wave-uniform -> weight rows come in via s_load (scalar cache);
        // each v_fmac is VGPR(z1) * SGPR(weight) -> 1 instr/MAC, no VMEM.
        float v0 = out_b[0], v1 = out_b[1], v2 = out_b[2];
        #pragma unroll 1
        for (int o = 0; o < HID; ++o) {
            float h = h2_b[o];
            float g = g2_b[o];
            const float* hw = h2_w + o * HID;
            const float* gw = g2_w + o * HID;
            sfor<0, HID>([&](auto icc) {
                constexpr int i = decltype(icc)::value;
                h = fmaf(hw[i], z1[i], h);
                g = fmaf(gw[i], z1[i], g);
            });
            float a = fmaxf(h * sigm(g), 0.0f);
            v0 = fmaf(out_w[o],           a, v0);
            v1 = fmaf(out_w[HID + o],     a, v1);
            v2 = fmaf(out_w[2 * HID + o], a, v2);
        }

        const float kx = tanh_fast(v0) * 0.5f;
        const float ky = tanh_fast(v1) * 0.5f;
        const float kz = tanh_fast(v2) * 0.5f;

        if (s == 0) {
            k1x = kx; k1y = ky; k1z = kz;
            ax = kx; ay = ky; az = kz;
        } else if (s == 1) {
            k2x = kx; k2y = ky; k2z = kz;
            ax = fmaf(3.0f, kx, ax); ay = fmaf(3.0f, ky, ay); az = fmaf(3.0f, kz, az);
        } else if (s == 2) {
            k3x = kx; k3y = ky; k3z = kz;
            ax = fmaf(3.0f, kx, ax); ay = fmaf(3.0f, ky, ay); az = fmaf(3.0f, kz, az);
        } else {
            ax += kx; ay += ky; az += kz;
        }
    }

    y[base]           = fmaf(0.125f, ax, xc0);
    y[base + NPT]     = fmaf(0.125f, ay, xc1);
    y[base + 2 * NPT] = fmaf(0.125f, az, xc2);
}

extern "C" void kernel_launch(void* const* d_in, const int* in_sizes, int n_in,
                              void* d_out, int out_size, void* d_ws, size_t ws_size,
                              hipStream_t stream) {
    (void)in_sizes; (void)n_in; (void)d_ws; (void)ws_size; (void)out_size;
    const float* x0    = (const float*)d_in[0];
    const float* h1_w  = (const float*)d_in[1];
    const float* h1_b  = (const float*)d_in[2];
    const float* g1_w  = (const float*)d_in[3];
    const float* g1_b  = (const float*)d_in[4];
    const float* h2_w  = (const float*)d_in[5];
    const float* h2_b  = (const float*)d_in[6];
    const float* g2_w  = (const float*)d_in[7];
    const float* g2_b  = (const float*)d_in[8];
    const float* out_w = (const float*)d_in[9];
    const float* out_b = (const float*)d_in[10];
    float* y = (float*)d_out;

    const int total = BATCH * NPT;
    const int block = 256;
    const int grid  = (total + block - 1) / block;
    node_rk4_kernel<<<grid, block, 0, stream>>>(
        x0, h1_w, h1_b, g1_w, g1_b, h2_w, h2_b, g2_w, g2_b, out_w, out_b, y);
}

// Round 3
// 414.155 us; speedup vs baseline: 41.4110x; 6.1482x over previous
//
#include <hip/hip_runtime.h>
#include <math.h>
#include <utility>

typedef __attribute__((ext_vector_type(8))) short    bf16x8;
typedef __attribute__((ext_vector_type(4))) float    f32x4;
typedef __attribute__((ext_vector_type(2))) unsigned u32x2;

template<int I, int N, class F>
__device__ __forceinline__ void sfor(F&& f) {
    if constexpr (I < N) { f(std::integral_constant<int, I>{}); sfor<I + 1, N>(static_cast<F&&>(f)); }
}

#define NPT    50000
#define NTILES 6250     // 400000 pts / 64 per tile, exact
#define ZIN_S  40       // shorts per zin row (80 B, 16B-aligned)
#define Z_S    136      // shorts per z1/z2 row (272 B, 16B-aligned)

static __device__ __forceinline__ float sigm(float x) { return __fdividef(1.f, 1.f + __expf(-x)); }
static __device__ __forceinline__ float tanh_fast(float x) {
    float xc = fminf(fmaxf(x, -15.f), 15.f);
    float e  = __expf(2.f * xc);
    return __fdividef(e - 1.f, e + 1.f);
}
static __device__ __forceinline__ unsigned short bf16r(float f) {   // RNE f32->bf16
    unsigned u = __builtin_bit_cast(unsigned, f);
    u += 0x7FFFu + ((u >> 16) & 1u);
    return (unsigned short)(u >> 16);
}
static __device__ __forceinline__ unsigned packbf(float a, float b) {
    return (unsigned)bf16r(a) | ((unsigned)bf16r(b) << 16);
}
static __device__ __forceinline__ f32x4 mfma16(bf16x8 a, bf16x8 b, f32x4 c) {
    return __builtin_amdgcn_mfma_f32_16x16x32_bf16(a, b, c, 0, 0, 0);
}

// Block = 256 thr = 4 waves. Each tile-iteration: 64 points.
// Wave w owns output channels [32w, 32w+32) for layers 1&2 (A-frags resident in
// VGPRs), and owns points [16w,16w+16) for RK4 state / out-layer.
// Activations pass through LDS in B-frag layout [p][k] (k contiguous bf16).
__global__ __launch_bounds__(256, 2) void node_rk4_mfma(
    const float* __restrict__ x0,
    const float* __restrict__ h1_w, const float* __restrict__ h1_b,
    const float* __restrict__ g1_w, const float* __restrict__ g1_b,
    const float* __restrict__ h2_w, const float* __restrict__ h2_b,
    const float* __restrict__ g2_w, const float* __restrict__ g2_b,
    const float* __restrict__ out_w, const float* __restrict__ out_b,
    float* __restrict__ y)
{
    __shared__ __align__(16) short zin[64 * ZIN_S];
    __shared__ __align__(16) short z1s[64 * Z_S];
    __shared__ __align__(16) short z2s[64 * Z_S];

    const int tid  = threadIdx.x;
    const int w    = tid >> 6;        // wave id 0..3
    const int lane = tid & 63;
    const int q    = lane >> 4;       // quad 0..3
    const int m    = lane & 15;       // MFMA row (A) / col (B,C)

    // ---------------- weight preload (once per block) ----------------
    bf16x8 a2h[2][4], a2g[2][4];      // layer2 A-frags: [mtile][kstep]
    bf16x8 a1h[2],    a1g[2];         // layer1 A-frags (K padded 4->32)
    bf16x8 aow[4];                    // out-layer A-frags (M padded 3->16)
    f32x4  b2h[2], b2g[2], b1h[2], b1g[2];   // per-(mtile,reg) biases

    sfor<0, 2>([&](auto MT) {
        constexpr int mt = MT.value;
        const int row = 32 * w + 16 * mt + m;
        sfor<0, 4>([&](auto KS) {
            constexpr int ks = KS.value;
            const float* s1 = h2_w + row * 128 + ks * 32 + q * 8;
            const float* s2 = g2_w + row * 128 + ks * 32 + q * 8;
            bf16x8 t1, t2;
            sfor<0, 8>([&](auto J) {
                constexpr int j = J.value;
                t1[j] = (short)bf16r(s1[j]);
                t2[j] = (short)bf16r(s2[j]);
            });
            a2h[mt][ks] = t1; a2g[mt][ks] = t2;
        });
        bf16x8 t1 = {0,0,0,0,0,0,0,0}, t2 = {0,0,0,0,0,0,0,0};
        if (q == 0) {
            sfor<0, 4>([&](auto J) {
                constexpr int j = J.value;
                t1[j] = (short)bf16r(h1_w[row * 4 + j]);
                t2[j] = (short)bf16r(g1_w[row * 4 + j]);
            });
        }
        a1h[mt] = t1; a1g[mt] = t2;
        const int ob = 32 * w + 16 * mt + 4 * q;
        f32x4 bh, bg, ch, cg;
        sfor<0, 4>([&](auto R) {
            constexpr int r = R.value;
            bh[r] = h2_b[ob + r]; bg[r] = g2_b[ob + r];
            ch[r] = h1_b[ob + r]; cg[r] = g1_b[ob + r];
        });
        b2h[mt] = bh; b2g[mt] = bg; b1h[mt] = ch; b1g[mt] = cg;
    });
    sfor<0, 4>([&](auto KS) {
        constexpr int ks = KS.value;
        bf16x8 t = {0,0,0,0,0,0,0,0};
        if (m < 3) {
            sfor<0, 8>([&](auto J) {
                constexpr int j = J.value;
                t[j] = (short)bf16r(out_w[m * 128 + ks * 32 + q * 8 + j]);
            });
        }
        aow[ks] = t;
    });
    const float ob0 = out_b[0], ob1 = out_b[1], ob2 = out_b[2];

    // zero zin (pad rows k=4..31 must be 0 for the K-padded layer1 MFMA)
    for (int i = tid; i < 64 * ZIN_S / 2; i += 256) ((unsigned*)zin)[i] = 0u;
    __syncthreads();

    const f32x4 zero4 = {0.f, 0.f, 0.f, 0.f};
    const float third = 1.0f / 3.0f;

    for (int tile = blockIdx.x; tile < NTILES; tile += gridDim.x) {
        float xc0 = 0.f, xc1 = 0.f, xc2 = 0.f;
        int gbase = 0;
        if (lane < 16) {
            const int pg = tile * 64 + w * 16 + lane;
            const int bb = pg / NPT;
            const int nn = pg - bb * NPT;
            gbase = bb * 3 * NPT + nn;
            xc0 = x0[gbase]; xc1 = x0[gbase + NPT]; xc2 = x0[gbase + 2 * NPT];
        }
        float k1x=0,k1y=0,k1z=0, k2x=0,k2y=0,k2z=0, k3x=0,k3y=0,k3z=0;
        float ax=0, ay=0, az=0;

        #pragma unroll 1
        for (int s = 0; s < 4; ++s) {
            // ---- stage input -> zin (B-frag rows, lanes 0-15 per wave) ----
            if (lane < 16) {
                float zi0, zi1, zi2, tt;
                if (s == 0)      { zi0 = xc0; zi1 = xc1; zi2 = xc2; tt = 0.f; }
                else if (s == 1) { zi0 = fmaf(k1x, third, xc0);
                                   zi1 = fmaf(k1y, third, xc1);
                                   zi2 = fmaf(k1z, third, xc2); tt = third; }
                else if (s == 2) { zi0 = xc0 + (k2x - k1x * third);
                                   zi1 = xc1 + (k2y - k1y * third);
                                   zi2 = xc2 + (k2z - k1z * third); tt = 2.f * third; }
                else             { zi0 = xc0 + (k1x - k2x + k3x);
                                   zi1 = xc1 + (k1y - k2y + k3y);
                                   zi2 = xc2 + (k1z - k2z + k3z); tt = 1.f; }
                u32x2 pk = { packbf(zi0, zi1), packbf(zi2, tt) };
                *reinterpret_cast<u32x2*>(&zin[(w * 16 + lane) * ZIN_S]) = pk;
            }
            __syncthreads();

            // ---- layer 1 (4->128 via K-padded MFMA) ----
            f32x4 c1h[2][4], c1g[2][4];
            sfor<0, 2>([&](auto MT) { sfor<0, 4>([&](auto NT) {
                c1h[MT.value][NT.value] = zero4; c1g[MT.value][NT.value] = zero4; }); });
            sfor<0, 4>([&](auto NT) {
                constexpr int nt = NT.value;
                bf16x8 bf = *reinterpret_cast<const bf16x8*>(&zin[(nt * 16 + m) * ZIN_S + q * 8]);
                sfor<0, 2>([&](auto MT) {
                    constexpr int mt = MT.value;
                    c1h[mt][nt] = mfma16(a1h[mt], bf, c1h[mt][nt]);
                    c1g[mt][nt] = mfma16(a1g[mt], bf, c1g[mt][nt]);
                });
            });
            // gate + write z1 B-frags
            sfor<0, 2>([&](auto MT) { sfor<0, 4>([&](auto NT) {
                constexpr int mt = MT.value, nt = NT.value;
                f32x4 h = c1h[mt][nt] + b1h[mt];
                f32x4 g = c1g[mt][nt] + b1g[mt];
                float z0 = fmaxf(h[0] * sigm(g[0]), 0.f);
                float z1v = fmaxf(h[1] * sigm(g[1]), 0.f);
                float z2v = fmaxf(h[2] * sigm(g[2]), 0.f);
                float z3 = fmaxf(h[3] * sigm(g[3]), 0.f);
                u32x2 pk = { packbf(z0, z1v), packbf(z2v, z3) };
                *reinterpret_cast<u32x2*>(&z1s[(nt * 16 + m) * Z_S + 32 * w + 16 * mt + 4 * q]) = pk;
            }); });
            __syncthreads();

            // ---- layer 2 (128->128) ----
            f32x4 c2h[2][4], c2g[2][4];
            sfor<0, 2>([&](auto MT) { sfor<0, 4>([&](auto NT) {
                c2h[MT.value][NT.value] = zero4; c2g[MT.value][NT.value] = zero4; }); });
            sfor<0, 4>([&](auto KS) {
                constexpr int ks = KS.value;
                sfor<0, 4>([&](auto NT) {
                    constexpr int nt = NT.value;
                    bf16x8 bf = *reinterpret_cast<const bf16x8*>(&z1s[(nt * 16 + m) * Z_S + ks * 32 + q * 8]);
                    sfor<0, 2>([&](auto MT) {
                        constexpr int mt = MT.value;
                        c2h[mt][nt] = mfma16(a2h[mt][ks], bf, c2h[mt][nt]);
                        c2g[mt][nt] = mfma16(a2g[mt][ks], bf, c2g[mt][nt]);
                    });
                });
            });
            // gate + write z2 B-frags
            sfor<0, 2>([&](auto MT) { sfor<0, 4>([&](auto NT) {
                constexpr int mt = MT.value, nt = NT.value;
                f32x4 h = c2h[mt][nt] + b2h[mt];
                f32x4 g = c2g[mt][nt] + b2g[mt];
                float z0 = fmaxf(h[0] * sigm(g[0]), 0.f);
                float z1v = fmaxf(h[1] * sigm(g[1]), 0.f);
                float z2v = fmaxf(h[2] * sigm(g[2]), 0.f);
                float z3 = fmaxf(h[3] * sigm(g[3]), 0.f);
                u32x2 pk = { packbf(z0, z1v), packbf(z2v, z3) };
                *reinterpret_cast<u32x2*>(&z2s[(nt * 16 + m) * Z_S + 32 * w + 16 * mt + 4 * q]) = pk;
            }); });
            __syncthreads();

            // ---- out layer (128->3, M padded to 16); wave w takes points [16w,16w+16) ----
            f32x4 vc = zero4;
            sfor<0, 4>([&](auto KS) {
                constexpr int ks = KS.value;
                bf16x8 bf = *reinterpret_cast<const bf16x8*>(&z2s[(w * 16 + m) * Z_S + ks * 32 + q * 8]);
                vc = mfma16(aow[ks], bf, vc);
            });
            // channels live in quad-0 regs 0..2 (C row = 4q+r)
            const float kx = tanh_fast(vc[0] + ob0) * 0.5f;
            const float ky = tanh_fast(vc[1] + ob1) * 0.5f;
            const float kz = tanh_fast(vc[2] + ob2) * 0.5f;

            if (s == 0)      { k1x=kx;k1y=ky;k1z=kz; ax=kx;ay=ky;az=kz; }
            else if (s == 1) { k2x=kx;k2y=ky;k2z=kz;
                               ax=fmaf(3.f,kx,ax); ay=fmaf(3.f,ky,ay); az=fmaf(3.f,kz,az); }
            else if (s == 2) { k3x=kx;k3y=ky;k3z=kz;
                               ax=fmaf(3.f,kx,ax); ay=fmaf(3.f,ky,ay); az=fmaf(3.f,kz,az); }
            else             { ax+=kx; ay+=ky; az+=kz; }
        }

        if (lane < 16) {
            y[gbase]            = fmaf(0.125f, ax, xc0);
            y[gbase + NPT]      = fmaf(0.125f, ay, xc1);
            y[gbase + 2 * NPT]  = fmaf(0.125f, az, xc2);
        }
    }
}

extern "C" void kernel_launch(void* const* d_in, const int* in_sizes, int n_in,
                              void* d_out, int out_size, void* d_ws, size_t ws_size,
                              hipStream_t stream) {
    (void)in_sizes; (void)n_in; (void)d_ws; (void)ws_size; (void)out_size;
    const float* x0    = (const float*)d_in[0];
    const float* h1_w  = (const float*)d_in[1];
    const float* h1_b  = (const float*)d_in[2];
    const float* g1_w  = (const float*)d_in[3];
    const float* g1_b  = (const float*)d_in[4];
    const float* h2_w  = (const float*)d_in[5];
    const float* h2_b  = (const float*)d_in[6];
    const float* g2_w  = (const float*)d_in[7];
    const float* g2_b  = (const float*)d_in[8];
    const float* out_w = (const float*)d_in[9];
    const float* out_b = (const float*)d_in[10];
    float* y = (float*)d_out;

    // 6250 tiles / 1250 blocks = exactly 5 tiles per block (weights preloaded once per block)
    node_rk4_mfma<<<1250, 256, 0, stream>>>(
        x0, h1_w, h1_b, g1_w, g1_b, h2_w, h2_b, g2_w, g2_b, out_w, out_b, y);
}